// Round 7
// baseline (537.877 us; speedup 1.0000x reference)
//
#include <hip/hip_runtime.h>
#include <hip/hip_bf16.h>
#include <math.h>
#include <stdint.h>

#define NN 50000
#define NE 400000

typedef __attribute__((ext_vector_type(8))) short short8;
typedef __attribute__((ext_vector_type(4))) float f32x4;

// bf16 weight workspace layout (element offsets)
#define OFF_WE1T 0           // [128][320]
#define OFF_WE2T 40960       // [128][128]
#define OFF_WN1T 57344       // [128][256]
#define OFF_WN2T 90112       // [128][128]
#define OFF_WC1T 106496      // [64][128]
#define W_TOTAL  114688

#define NFB_ITEMS 800000     // NN*128/8

__device__ __forceinline__ float silu_f(float x) {
    return x * (1.0f / (1.0f + __expf(-x)));
}
__device__ __forceinline__ short f2bf(float f) {
    __hip_bfloat16 b = __float2bfloat16(f);
    return *reinterpret_cast<short*>(&b);
}
__device__ __forceinline__ short8 cvt8(float4 a, float4 b) {
    short8 r;
    r[0] = f2bf(a.x); r[1] = f2bf(a.y); r[2] = f2bf(a.z); r[3] = f2bf(a.w);
    r[4] = f2bf(b.x); r[5] = f2bf(b.y); r[6] = f2bf(b.z); r[7] = f2bf(b.w);
    return r;
}

// async global->LDS, 16B per lane; LDS dest = (wave-uniform base) + lane*16
__device__ __forceinline__ void gload16(const short* g, short* l) {
    __builtin_amdgcn_global_load_lds(
        (const __attribute__((address_space(1))) void*)g,
        (__attribute__((address_space(3))) void*)l, 16, 0, 0);
}

// ---------------- zero aggr/coord accumulators ----------------
__global__ void zero_kernel(float4* __restrict__ p, int n4) {
    int i = blockIdx.x * blockDim.x + threadIdx.x;
    int st = gridDim.x * blockDim.x;
    for (; i < n4; i += st) p[i] = make_float4(0.f, 0.f, 0.f, 0.f);
}

// ---------------- prep: weights fp32[K][N] -> bf16[N][K]; nf -> bf16 ----------------
__global__ __launch_bounds__(256) void prep_kernel(
    const float* __restrict__ We1, const float* __restrict__ We2,
    const float* __restrict__ Wn1, const float* __restrict__ Wn2,
    const float* __restrict__ Wc1, const float* __restrict__ nf,
    short* __restrict__ wb, short* __restrict__ nfb, int full)
{
    const int i = blockIdx.x * 256 + threadIdx.x;
    if (i < W_TOTAL) {
        const float* src; int N, n, k, rel;
        if (i < OFF_WE2T)      { rel = i;            src = We1; N = 128; n = rel / 320; k = rel % 320; }
        else if (i < OFF_WN1T) { rel = i - OFF_WE2T; src = We2; N = 128; n = rel / 128; k = rel % 128; }
        else if (i < OFF_WN2T) { rel = i - OFF_WN1T; src = Wn1; N = 128; n = rel / 256; k = rel % 256; }
        else if (i < OFF_WC1T) { rel = i - OFF_WN2T; src = Wn2; N = 128; n = rel / 128; k = rel % 128; }
        else                   { rel = i - OFF_WC1T; src = Wc1; N = 64;  n = rel / 128; k = rel % 128; }
        wb[i] = f2bf(src[(size_t)k * N + n]);
    } else if (full && i < W_TOTAL + NFB_ITEMS) {
        const int j = i - W_TOTAL;
        const float4 a = *(const float4*)&nf[(size_t)j * 8];
        const float4 b = *(const float4*)&nf[(size_t)j * 8 + 4];
        *(short8*)&nfb[(size_t)j * 8] = cvt8(a, b);
    }
}

// ---------------- edge pipeline: M=16 edges/wave, staged gathers, high occupancy ----------------
// 64 edges/block, 4 waves, 16 edges/wave. 8KB LDS/wave (stage, reused as Hs)
// -> 32KB/block -> 5 blocks/CU; VGPR-capped for 5 waves/SIMD (~20 waves/CU).
// Gathers land in LDS via global_load_lds (fragment layout, zero VGPR);
// per-wave pipeline is barrier-free.
template<bool STAGED>
__global__ __launch_bounds__(256, 5) void edge_kernel(
    const float* __restrict__ nf, const short* __restrict__ nfb,
    const float* __restrict__ ea,
    const float* __restrict__ coords, const int* __restrict__ ei,
    const short* __restrict__ wb,
    const float* __restrict__ be1, const float* __restrict__ be2,
    const float* __restrict__ bc1, const float* __restrict__ bc2,
    const float* __restrict__ Wc2f,
    float* __restrict__ aggr, float* __restrict__ coord_acc)
{
    __shared__ short smem[4][4096];   // 8KB per wave

    const int tid = threadIdx.x;
    const int wv = tid >> 6, lane = tid & 63, le = lane & 15, g = lane >> 4;
    const int base = (blockIdx.x * 4 + wv) * 16;
    short* stage = smem[wv];
    short (*Hs)[136] = (short(*)[136])stage;

    const int s0 = ei[base + le];
    const int d0 = ei[NE + base + le];

    // stage the 8 gathered nf chunks (src kc 0..3, dst kc 4..7); 1KB each
    if constexpr (STAGED) {
        #pragma unroll
        for (int kc = 0; kc < 8; ++kc) {
            const int r0 = (kc < 4) ? s0 : d0;
            gload16(nfb + (size_t)r0 * 128 + (kc & 3) * 32 + g * 8, stage + kc * 512);
        }
    }
    // edge_attr (coalesced fp32) -> registers
    float4 eaf[2][2];
    #pragma unroll
    for (int q = 0; q < 2; ++q) {
        const float* pe = ea + (size_t)(base + le) * 64 + q * 32 + g * 8;
        eaf[q][0] = *(const float4*)pe;
        eaf[q][1] = *(const float4*)(pe + 4);
    }
    if constexpr (STAGED) {
        asm volatile("s_waitcnt vmcnt(0)" ::: "memory");
        __builtin_amdgcn_sched_barrier(0);
    }

    // ===== MLP1: h1 = silu(A @ We1 + be1), K=320, N=128
    f32x4 acc[8];
    #pragma unroll
    for (int t = 0; t < 8; ++t) acc[t] = (f32x4){0.f, 0.f, 0.f, 0.f};

    const short* w1 = wb + OFF_WE1T;
    #pragma unroll
    for (int kc = 0; kc < 10; ++kc) {
        const int gk = kc * 32 + g * 8;
        short8 a0;
        if (kc < 8) {
            if constexpr (STAGED) {
                a0 = *(const short8*)&stage[kc * 512 + lane * 8];
            } else {
                const int r0 = (kc < 4) ? s0 : d0;
                const float* p0 = nf + (size_t)r0 * 128 + (kc & 3) * 32 + g * 8;
                a0 = cvt8(*(const float4*)p0, *(const float4*)(p0 + 4));
            }
        } else {
            a0 = cvt8(eaf[kc - 8][0], eaf[kc - 8][1]);
        }
        short8 bfv[8];
        #pragma unroll
        for (int t = 0; t < 8; ++t)
            bfv[t] = *(const short8*)(w1 + (size_t)(t * 16 + le) * 320 + gk);
        #pragma unroll
        for (int t = 0; t < 8; ++t)
            acc[t] = __builtin_amdgcn_mfma_f32_16x16x32_bf16(a0, bfv[t], acc[t], 0, 0, 0);
    }

    // h1 epilogue -> Hs (reuses stage; all stage reads complete)
    #pragma unroll
    for (int t = 0; t < 8; ++t) {
        const float b1 = be1[t * 16 + le];
        #pragma unroll
        for (int r = 0; r < 4; ++r)
            Hs[g * 4 + r][t * 16 + le] = f2bf(silu_f(acc[t][r] + b1));
    }

    // ===== MLP2: h2 = silu(h1 @ We2 + be2), K=128
    f32x4 acc2[8];
    #pragma unroll
    for (int t = 0; t < 8; ++t) acc2[t] = (f32x4){0.f, 0.f, 0.f, 0.f};

    const short* w2 = wb + OFF_WE2T;
    #pragma unroll
    for (int kc = 0; kc < 4; ++kc) {
        const int gk = kc * 32 + g * 8;
        const short8 a0 = *(const short8*)&Hs[le][gk];
        short8 bfv[8];
        #pragma unroll
        for (int t = 0; t < 8; ++t)
            bfv[t] = *(const short8*)(w2 + (size_t)(t * 16 + le) * 128 + gk);
        #pragma unroll
        for (int t = 0; t < 8; ++t)
            acc2[t] = __builtin_amdgcn_mfma_f32_16x16x32_bf16(a0, bfv[t], acc2[t], 0, 0, 0);
    }

    // h2 epilogue: quarter-wave contiguous atomics + Hs overwrite
    int dstv[4];
    #pragma unroll
    for (int r = 0; r < 4; ++r) dstv[r] = __shfl(d0, g * 4 + r);

    #pragma unroll
    for (int t = 0; t < 8; ++t) {
        const float b2 = be2[t * 16 + le];
        #pragma unroll
        for (int r = 0; r < 4; ++r) {
            const float v = silu_f(acc2[t][r] + b2);
            atomicAdd(&aggr[(size_t)dstv[r] * 128 + t * 16 + le], v);
            Hs[g * 4 + r][t * 16 + le] = f2bf(v);
        }
    }

    // ===== coord MLP: c1 = silu(h2 @ Wc1 + bc1), K=128, N=64
    f32x4 acc3[4];
    #pragma unroll
    for (int t = 0; t < 4; ++t) acc3[t] = (f32x4){0.f, 0.f, 0.f, 0.f};

    const short* wc = wb + OFF_WC1T;
    #pragma unroll
    for (int kc = 0; kc < 4; ++kc) {
        const int gk = kc * 32 + g * 8;
        const short8 a0 = *(const short8*)&Hs[le][gk];
        short8 bfv[4];
        #pragma unroll
        for (int t = 0; t < 4; ++t)
            bfv[t] = *(const short8*)(wc + (size_t)(t * 16 + le) * 128 + gk);
        #pragma unroll
        for (int t = 0; t < 4; ++t)
            acc3[t] = __builtin_amdgcn_mfma_f32_16x16x32_bf16(a0, bfv[t], acc3[t], 0, 0, 0);
    }

    // coord_w partials + butterfly over le lanes
    float part[4];
    #pragma unroll
    for (int r = 0; r < 4; ++r) part[r] = 0.f;
    #pragma unroll
    for (int t = 0; t < 4; ++t) {
        const float bc = bc1[t * 16 + le];
        const float w2c = Wc2f[t * 16 + le];
        #pragma unroll
        for (int r = 0; r < 4; ++r)
            part[r] += silu_f(acc3[t][r] + bc) * w2c;
    }
    #pragma unroll
    for (int mask = 1; mask <= 8; mask <<= 1)
        #pragma unroll
        for (int r = 0; r < 4; ++r)
            part[r] += __shfl_xor(part[r], mask);

    // owner lanes le<4 handle edge g*4+le; shfl pre-branch (all lanes active)
    const int rr = le & 3;
    const int sA = __shfl(s0, g * 4 + rr);
    const int dA = __shfl(d0, g * 4 + rr);

    if (le < 4) {
        const float v = (rr == 0) ? part[0] : (rr == 1) ? part[1] : (rr == 2) ? part[2] : part[3];
        const float dx = coords[3 * sA + 0] - coords[3 * dA + 0];
        const float dy = coords[3 * sA + 1] - coords[3 * dA + 1];
        const float dz = coords[3 * sA + 2] - coords[3 * dA + 2];
        const float wq = v + bc2[0];
        const float inv = wq / (sqrtf(dx * dx + dy * dy + dz * dz) + 1e-8f);
        atomicAdd(&coord_acc[3 * dA + 0], dx * inv);
        atomicAdd(&coord_acc[3 * dA + 1], dy * inv);
        atomicAdd(&coord_acc[3 * dA + 2], dz * inv);
    }
}

// ---------------- node update (MFMA, barrier-free) ----------------
template<bool BF16NF>
__global__ __launch_bounds__(256, 2) void node_kernel(
    const float* __restrict__ nf, const short* __restrict__ nfb,
    const float* __restrict__ coords, const short* __restrict__ wb,
    const float* __restrict__ bn1, const float* __restrict__ bn2,
    const float* __restrict__ aggr, const float* __restrict__ coord_acc,
    float* __restrict__ out)
{
    __shared__ short Hs[128][136];

    const int tid = threadIdx.x;
    const int wv = tid >> 6, lane = tid & 63, le = lane & 15, grp = lane >> 4;
    const int nb = blockIdx.x * 128, wbase = wv * 32;
    const int row0 = min(nb + wbase + le, NN - 1);
    const int row1 = min(nb + wbase + 16 + le, NN - 1);

    // MLP1: K=256 ([nf | aggr])
    f32x4 acc[2][8];
    #pragma unroll
    for (int m = 0; m < 2; ++m)
        #pragma unroll
        for (int t = 0; t < 8; ++t) acc[m][t] = (f32x4){0.f, 0.f, 0.f, 0.f};

    const short* w1 = wb + OFF_WN1T;
    #pragma unroll
    for (int kc = 0; kc < 8; ++kc) {
        const int gk = kc * 32 + grp * 8;
        short8 a0, a1;
        if (kc < 4) {
            if (BF16NF) {
                a0 = *(const short8*)&nfb[(size_t)row0 * 128 + gk];
                a1 = *(const short8*)&nfb[(size_t)row1 * 128 + gk];
            } else {
                const float* p0 = nf + (size_t)row0 * 128 + gk;
                const float* p1 = nf + (size_t)row1 * 128 + gk;
                a0 = cvt8(*(const float4*)p0, *(const float4*)(p0 + 4));
                a1 = cvt8(*(const float4*)p1, *(const float4*)(p1 + 4));
            }
        } else {
            const float* p0 = aggr + (size_t)row0 * 128 + gk - 128;
            const float* p1 = aggr + (size_t)row1 * 128 + gk - 128;
            a0 = cvt8(*(const float4*)p0, *(const float4*)(p0 + 4));
            a1 = cvt8(*(const float4*)p1, *(const float4*)(p1 + 4));
        }
        short8 bfv[8];
        #pragma unroll
        for (int t = 0; t < 8; ++t)
            bfv[t] = *(const short8*)(w1 + (size_t)(t * 16 + le) * 256 + gk);
        #pragma unroll
        for (int t = 0; t < 8; ++t) {
            acc[0][t] = __builtin_amdgcn_mfma_f32_16x16x32_bf16(a0, bfv[t], acc[0][t], 0, 0, 0);
            acc[1][t] = __builtin_amdgcn_mfma_f32_16x16x32_bf16(a1, bfv[t], acc[1][t], 0, 0, 0);
        }
    }
    #pragma unroll
    for (int t = 0; t < 8; ++t) {
        const float b1 = bn1[t * 16 + le];
        #pragma unroll
        for (int m = 0; m < 2; ++m)
            #pragma unroll
            for (int r = 0; r < 4; ++r)
                Hs[wbase + m * 16 + grp * 4 + r][t * 16 + le] = f2bf(silu_f(acc[m][t][r] + b1));
    }

    // MLP2: K=128, then residual
    f32x4 acc2[2][8];
    #pragma unroll
    for (int m = 0; m < 2; ++m)
        #pragma unroll
        for (int t = 0; t < 8; ++t) acc2[m][t] = (f32x4){0.f, 0.f, 0.f, 0.f};

    const short* w2 = wb + OFF_WN2T;
    #pragma unroll
    for (int kc = 0; kc < 4; ++kc) {
        const int gk = kc * 32 + grp * 8;
        const short8 a0 = *(const short8*)&Hs[wbase + le][gk];
        const short8 a1 = *(const short8*)&Hs[wbase + 16 + le][gk];
        short8 bfv[8];
        #pragma unroll
        for (int t = 0; t < 8; ++t)
            bfv[t] = *(const short8*)(w2 + (size_t)(t * 16 + le) * 128 + gk);
        #pragma unroll
        for (int t = 0; t < 8; ++t) {
            acc2[0][t] = __builtin_amdgcn_mfma_f32_16x16x32_bf16(a0, bfv[t], acc2[0][t], 0, 0, 0);
            acc2[1][t] = __builtin_amdgcn_mfma_f32_16x16x32_bf16(a1, bfv[t], acc2[1][t], 0, 0, 0);
        }
    }
    #pragma unroll
    for (int t = 0; t < 8; ++t) {
        const float b2 = bn2[t * 16 + le];
        #pragma unroll
        for (int m = 0; m < 2; ++m)
            #pragma unroll
            for (int r = 0; r < 4; ++r) {
                const int row = nb + wbase + m * 16 + grp * 4 + r;
                if (row < NN) {
                    const int c = t * 16 + le;
                    out[(size_t)row * 128 + c] = acc2[m][t][r] + b2 + nf[(size_t)row * 128 + c];
                }
            }
    }

    // coords epilogue
    for (int i = tid; i < 384; i += 256) {
        const int n = nb + i / 3, j = i % 3;
        if (n < NN)
            out[(size_t)NN * 128 + 3 * n + j] = coords[3 * n + j] + coord_acc[3 * n + j];
    }
}

extern "C" void kernel_launch(void* const* d_in, const int* in_sizes, int n_in,
                              void* d_out, int out_size, void* d_ws, size_t ws_size,
                              hipStream_t stream)
{
    const float* node_feat  = (const float*)d_in[0];
    const float* edge_attr  = (const float*)d_in[1];
    const float* coords     = (const float*)d_in[2];
    const int*   edge_index = (const int*)d_in[3];
    const float* We1 = (const float*)d_in[4];
    const float* be1 = (const float*)d_in[5];
    const float* We2 = (const float*)d_in[6];
    const float* be2 = (const float*)d_in[7];
    const float* Wn1 = (const float*)d_in[8];
    const float* bn1 = (const float*)d_in[9];
    const float* Wn2 = (const float*)d_in[10];
    const float* bn2 = (const float*)d_in[11];
    const float* Wc1 = (const float*)d_in[12];
    const float* bc1 = (const float*)d_in[13];
    const float* Wc2 = (const float*)d_in[14];
    const float* bc2 = (const float*)d_in[15];
    float* out = (float*)d_out;

    const size_t sz_wb   = (size_t)W_TOTAL * 2;            // 229 KB
    const size_t sz_agg  = (size_t)NN * 128 * 4;           // 25.6 MB
    const size_t sz_cac  = (size_t)NN * 3 * 4;             // 600 KB
    const size_t sz_nfb  = (size_t)NN * 128 * 2;           // 12.8 MB
    const size_t need_full = sz_wb + sz_agg + sz_cac + sz_nfb;   // ~39.3 MB
    (void)need_full;

    char* p = (char*)d_ws;
    short* wbf       = (short*)p;  p += sz_wb;
    float* aggr      = (float*)p;  p += sz_agg;
    float* coord_acc = (float*)p;  p += sz_cac;
    short* nfb       = (short*)p;

    const int n4 = (NN * 128 + NN * 3) / 4;   // re-zero accumulators every call
    const int eg = NE / 64;                   // 6250 blocks (4 waves x 16 edges)
    const int ng = (NN + 127) / 128;          // 391

    if (ws_size >= need_full) {
        const int pg = (W_TOTAL + NFB_ITEMS + 255) / 256;
        prep_kernel<<<pg, 256, 0, stream>>>(
            We1, We2, Wn1, Wn2, Wc1, node_feat, wbf, nfb, 1);
        zero_kernel<<<2048, 256, 0, stream>>>((float4*)aggr, n4);

        edge_kernel<true><<<eg, 256, 0, stream>>>(
            node_feat, nfb, edge_attr, coords, edge_index, wbf,
            be1, be2, bc1, bc2, Wc2, aggr, coord_acc);

        node_kernel<true><<<ng, 256, 0, stream>>>(
            node_feat, nfb, coords, wbf, bn1, bn2, aggr, coord_acc, out);
    } else {
        const int pg = (W_TOTAL + 255) / 256;
        prep_kernel<<<pg, 256, 0, stream>>>(
            We1, We2, Wn1, Wn2, Wc1, node_feat, wbf, nullptr, 0);
        zero_kernel<<<2048, 256, 0, stream>>>((float4*)aggr, n4);

        edge_kernel<false><<<eg, 256, 0, stream>>>(
            node_feat, nullptr, edge_attr, coords, edge_index, wbf,
            be1, be2, bc1, bc2, Wc2, aggr, coord_acc);

        node_kernel<false><<<ng, 256, 0, stream>>>(
            node_feat, nullptr, coords, wbf, bn1, bn2, aggr, coord_acc, out);
    }
}

// Round 8
// 390.021 us; speedup vs baseline: 1.3791x; 1.3791x over previous
//
#include <hip/hip_runtime.h>
#include <hip/hip_bf16.h>
#include <math.h>
#include <stdint.h>

#define NN 50000
#define NE 400000

typedef __attribute__((ext_vector_type(8))) short short8;
typedef __attribute__((ext_vector_type(4))) float f32x4;

// bf16 weight workspace layout (element offsets)
#define OFF_W1S  0           // [128][128]  We1 rows 0..127   (src half), transposed
#define OFF_W1D  16384       // [128][128]  We1 rows 128..255 (dst half)
#define OFF_W1E  32768       // [128][64]   We1 rows 256..319 (edge_attr part)
#define OFF_WE2T 40960       // [128][128]
#define OFF_WN1T 57344       // [128][256]
#define OFF_WN2T 90112       // [128][128]
#define OFF_WC1T 106496      // [64][128]
#define W_TOTAL  114688

__device__ __forceinline__ float silu_f(float x) {
    return x * (1.0f / (1.0f + __expf(-x)));
}
__device__ __forceinline__ short f2bf(float f) {
    __hip_bfloat16 b = __float2bfloat16(f);
    return *reinterpret_cast<short*>(&b);
}
__device__ __forceinline__ float bf2f(short s) {
    uint32_t u = ((uint32_t)(uint16_t)s) << 16;
    float f; __builtin_memcpy(&f, &u, 4); return f;
}
__device__ __forceinline__ short8 cvt8(float4 a, float4 b) {
    short8 r;
    r[0] = f2bf(a.x); r[1] = f2bf(a.y); r[2] = f2bf(a.z); r[3] = f2bf(a.w);
    r[4] = f2bf(b.x); r[5] = f2bf(b.y); r[6] = f2bf(b.z); r[7] = f2bf(b.w);
    return r;
}

// async global->LDS, 16B per lane; LDS dest = (wave-uniform base) + lane*16
__device__ __forceinline__ void gload16(const short* g, short* l) {
    __builtin_amdgcn_global_load_lds(
        (const __attribute__((address_space(1))) void*)g,
        (__attribute__((address_space(3))) void*)l, 16, 0, 0);
}

// ---------------- zero aggr/coord accumulators ----------------
__global__ void zero_kernel(float4* __restrict__ p, int n4) {
    int i = blockIdx.x * blockDim.x + threadIdx.x;
    int st = gridDim.x * blockDim.x;
    for (; i < n4; i += st) p[i] = make_float4(0.f, 0.f, 0.f, 0.f);
}

// ---------------- prep: weights fp32 [K][N] -> bf16 transposed [N][K] ----------------
__global__ __launch_bounds__(256) void prep_kernel(
    const float* __restrict__ We1, const float* __restrict__ We2,
    const float* __restrict__ Wn1, const float* __restrict__ Wn2,
    const float* __restrict__ Wc1, short* __restrict__ wb)
{
    const int i = blockIdx.x * 256 + threadIdx.x;
    if (i >= W_TOTAL) return;
    float v; int rel, n, k;
    if (i < OFF_W1D)       { rel = i;            n = rel >> 7; k = rel & 127; v = We1[k * 128 + n]; }
    else if (i < OFF_W1E)  { rel = i - OFF_W1D;  n = rel >> 7; k = rel & 127; v = We1[(k + 128) * 128 + n]; }
    else if (i < OFF_WE2T) { rel = i - OFF_W1E;  n = rel >> 6; k = rel & 63;  v = We1[(k + 256) * 128 + n]; }
    else if (i < OFF_WN1T) { rel = i - OFF_WE2T; n = rel >> 7; k = rel & 127; v = We2[k * 128 + n]; }
    else if (i < OFF_WN2T) { rel = i - OFF_WN1T; n = rel >> 8; k = rel & 255; v = Wn1[k * 128 + n]; }
    else if (i < OFF_WC1T) { rel = i - OFF_WN2T; n = rel >> 7; k = rel & 127; v = Wn2[k * 128 + n]; }
    else                   { rel = i - OFF_WC1T; n = rel >> 7; k = rel & 127; v = Wc1[k * 64 + n]; }
    wb[i] = f2bf(v);
}

// ---------------- ynode: Ys = nf @ We1_src, Yd = nf @ We1_dst (bf16 out) ----------------
// 128 nodes/block, 4 waves x 32 nodes. Moves the dominant per-edge K=256 work
// to a per-NODE dense GEMM (linearity of MLP1 pre-activation).
__global__ __launch_bounds__(256, 4) void ynode_kernel(
    const float* __restrict__ nf, const short* __restrict__ wb,
    short* __restrict__ ysb, short* __restrict__ ydb)
{
    const int tid = threadIdx.x;
    const int wv = tid >> 6, lane = tid & 63, le = lane & 15, grp = lane >> 4;
    const int nb = blockIdx.x * 128, wbase = wv * 32;
    const int row0 = min(nb + wbase + le, NN - 1);
    const int row1 = min(nb + wbase + 16 + le, NN - 1);

    #pragma unroll 1
    for (int pass = 0; pass < 2; ++pass) {
        const short* wt = wb + (pass ? OFF_W1D : OFF_W1S);
        short* op = pass ? ydb : ysb;

        f32x4 acc[2][8];
        #pragma unroll
        for (int m = 0; m < 2; ++m)
            #pragma unroll
            for (int t = 0; t < 8; ++t) acc[m][t] = (f32x4){0.f, 0.f, 0.f, 0.f};

        #pragma unroll
        for (int kc = 0; kc < 4; ++kc) {
            const int gk = kc * 32 + grp * 8;
            const float* p0 = nf + (size_t)row0 * 128 + gk;
            const float* p1 = nf + (size_t)row1 * 128 + gk;
            const short8 a0 = cvt8(*(const float4*)p0, *(const float4*)(p0 + 4));
            const short8 a1 = cvt8(*(const float4*)p1, *(const float4*)(p1 + 4));
            short8 bfv[8];
            #pragma unroll
            for (int t = 0; t < 8; ++t)
                bfv[t] = *(const short8*)(wt + (size_t)(t * 16 + le) * 128 + gk);
            #pragma unroll
            for (int t = 0; t < 8; ++t) {
                acc[0][t] = __builtin_amdgcn_mfma_f32_16x16x32_bf16(a0, bfv[t], acc[0][t], 0, 0, 0);
                acc[1][t] = __builtin_amdgcn_mfma_f32_16x16x32_bf16(a1, bfv[t], acc[1][t], 0, 0, 0);
            }
        }
        #pragma unroll
        for (int t = 0; t < 8; ++t)
            #pragma unroll
            for (int m = 0; m < 2; ++m)
                #pragma unroll
                for (int r = 0; r < 4; ++r) {
                    const int row = nb + wbase + m * 16 + grp * 4 + r;
                    if (row < NN)
                        op[(size_t)row * 128 + t * 16 + le] = f2bf(acc[m][t][r]);
                }
    }
}

// ---------------- edge pipeline: gather Ys/Yd + small ea-GEMM + MLP2 + coord ----------------
// 128 edges/block, 4 waves, 32 edges/wave. 16KB LDS/wave staged via global_load_lds:
//   shorts [0,4096)   : Ys[s] rows (stage layout), overwritten by h1
//   shorts [4096,8192): Yd[d] rows, overwritten by h2
// stage layout addr (row in tile, short8-chunk c8): (row>>4)*2048 + (c8>>2)*512
//   + ((c8&3)*16 + (row&15))*8   [matches gload16's base+lane*16B]
// Weight loads per wave: 64KB from L2 (was 128KB); MFMA 128 (was 256).
__global__ __launch_bounds__(256, 2) void edge_kernel(
    const short* __restrict__ ysb, const short* __restrict__ ydb,
    const float* __restrict__ ea, const float* __restrict__ coords,
    const int* __restrict__ ei, const short* __restrict__ wb,
    const float* __restrict__ be1, const float* __restrict__ be2,
    const float* __restrict__ bc1, const float* __restrict__ bc2,
    const float* __restrict__ Wc2f,
    float* __restrict__ aggr, float* __restrict__ coord_acc)
{
    __shared__ short smem[4][8192];   // 16KB per wave

    const int tid = threadIdx.x;
    const int wv = tid >> 6, lane = tid & 63, le = lane & 15, g = lane >> 4;
    const int base = (blockIdx.x * 4 + wv) * 32;
    short* stage = smem[wv];

    const int s0 = ei[base + le],      s1 = ei[base + 16 + le];
    const int d0 = ei[NE + base + le], d1 = ei[NE + base + 16 + le];

    // stage gathered Ys/Yd rows (16 instrs, zero VGPR, all in flight at once)
    #pragma unroll
    for (int q = 0; q < 4; ++q) {
        gload16(ysb + (size_t)s0 * 128 + q * 32 + g * 8, stage + q * 512);
        gload16(ysb + (size_t)s1 * 128 + q * 32 + g * 8, stage + 2048 + q * 512);
        gload16(ydb + (size_t)d0 * 128 + q * 32 + g * 8, stage + 4096 + q * 512);
        gload16(ydb + (size_t)d1 * 128 + q * 32 + g * 8, stage + 6144 + q * 512);
    }

    // ===== ea-part of MLP1: acc = ea @ W1E (K=64) — runs while stage is in flight
    f32x4 acc[2][8];
    #pragma unroll
    for (int m = 0; m < 2; ++m)
        #pragma unroll
        for (int t = 0; t < 8; ++t) acc[m][t] = (f32x4){0.f, 0.f, 0.f, 0.f};

    const short* w1e = wb + OFF_W1E;
    #pragma unroll
    for (int kc = 0; kc < 2; ++kc) {
        const int gk = kc * 32 + g * 8;
        const float* p0 = ea + (size_t)(base + le) * 64 + gk;
        const float* p1 = ea + (size_t)(base + 16 + le) * 64 + gk;
        const short8 a0 = cvt8(*(const float4*)p0, *(const float4*)(p0 + 4));
        const short8 a1 = cvt8(*(const float4*)p1, *(const float4*)(p1 + 4));
        short8 bfv[8];
        #pragma unroll
        for (int t = 0; t < 8; ++t)
            bfv[t] = *(const short8*)(w1e + (size_t)(t * 16 + le) * 64 + gk);
        #pragma unroll
        for (int t = 0; t < 8; ++t) {
            acc[0][t] = __builtin_amdgcn_mfma_f32_16x16x32_bf16(a0, bfv[t], acc[0][t], 0, 0, 0);
            acc[1][t] = __builtin_amdgcn_mfma_f32_16x16x32_bf16(a1, bfv[t], acc[1][t], 0, 0, 0);
        }
    }

    asm volatile("s_waitcnt vmcnt(0)" ::: "memory");
    __builtin_amdgcn_sched_barrier(0);

    // ===== h1 = silu(Ys[s] + Yd[d] + ea-part + be1); write into Ys region (stage layout)
    // Each (row,col) element is read and written by exactly one lane -> race-free.
    #pragma unroll
    for (int t = 0; t < 8; ++t) {
        const int col = t * 16 + le;
        const float b1 = be1[col];
        const int c8 = col >> 3, q = c8 >> 2, cc = c8 & 3, el = col & 7;
        #pragma unroll
        for (int m = 0; m < 2; ++m)
            #pragma unroll
            for (int r = 0; r < 4; ++r) {
                const int ad = m * 2048 + q * 512 + cc * 128 + (g * 4 + r) * 8 + el;
                const float v = silu_f(acc[m][t][r] + bf2f(stage[ad]) + bf2f(stage[4096 + ad]) + b1);
                stage[ad] = f2bf(v);
            }
    }

    // ===== MLP2: h2 = silu(h1 @ We2 + be2), K=128
    f32x4 acc2[2][8];
    #pragma unroll
    for (int m = 0; m < 2; ++m)
        #pragma unroll
        for (int t = 0; t < 8; ++t) acc2[m][t] = (f32x4){0.f, 0.f, 0.f, 0.f};

    const short* w2 = wb + OFF_WE2T;
    #pragma unroll
    for (int kc = 0; kc < 4; ++kc) {
        const int gk = kc * 32 + g * 8;
        const short8 a0 = *(const short8*)&stage[kc * 512 + g * 128 + le * 8];
        const short8 a1 = *(const short8*)&stage[2048 + kc * 512 + g * 128 + le * 8];
        short8 bfv[8];
        #pragma unroll
        for (int t = 0; t < 8; ++t)
            bfv[t] = *(const short8*)(w2 + (size_t)(t * 16 + le) * 128 + gk);
        #pragma unroll
        for (int t = 0; t < 8; ++t) {
            acc2[0][t] = __builtin_amdgcn_mfma_f32_16x16x32_bf16(a0, bfv[t], acc2[0][t], 0, 0, 0);
            acc2[1][t] = __builtin_amdgcn_mfma_f32_16x16x32_bf16(a1, bfv[t], acc2[1][t], 0, 0, 0);
        }
    }

    // h2 epilogue: quarter-wave contiguous atomics (proven) + write h2 into Yd region
    int dstv[2][4];
    #pragma unroll
    for (int r = 0; r < 4; ++r) {
        dstv[0][r] = __shfl(d0, g * 4 + r);
        dstv[1][r] = __shfl(d1, g * 4 + r);
    }
    #pragma unroll
    for (int t = 0; t < 8; ++t) {
        const int col = t * 16 + le;
        const float b2 = be2[col];
        const int c8 = col >> 3, q = c8 >> 2, cc = c8 & 3, el = col & 7;
        #pragma unroll
        for (int m = 0; m < 2; ++m)
            #pragma unroll
            for (int r = 0; r < 4; ++r) {
                const float v = silu_f(acc2[m][t][r] + b2);
                atomicAdd(&aggr[(size_t)dstv[m][r] * 128 + col], v);
                stage[4096 + m * 2048 + q * 512 + cc * 128 + (g * 4 + r) * 8 + el] = f2bf(v);
            }
    }

    // ===== coord MLP: c1 = silu(h2 @ Wc1 + bc1), K=128, N=64
    f32x4 acc3[2][4];
    #pragma unroll
    for (int m = 0; m < 2; ++m)
        #pragma unroll
        for (int t = 0; t < 4; ++t) acc3[m][t] = (f32x4){0.f, 0.f, 0.f, 0.f};

    const short* wc = wb + OFF_WC1T;
    #pragma unroll
    for (int kc = 0; kc < 4; ++kc) {
        const int gk = kc * 32 + g * 8;
        const short8 a0 = *(const short8*)&stage[4096 + kc * 512 + g * 128 + le * 8];
        const short8 a1 = *(const short8*)&stage[6144 + kc * 512 + g * 128 + le * 8];
        short8 bfv[4];
        #pragma unroll
        for (int t = 0; t < 4; ++t)
            bfv[t] = *(const short8*)(wc + (size_t)(t * 16 + le) * 128 + gk);
        #pragma unroll
        for (int t = 0; t < 4; ++t) {
            acc3[0][t] = __builtin_amdgcn_mfma_f32_16x16x32_bf16(a0, bfv[t], acc3[0][t], 0, 0, 0);
            acc3[1][t] = __builtin_amdgcn_mfma_f32_16x16x32_bf16(a1, bfv[t], acc3[1][t], 0, 0, 0);
        }
    }

    // coord_w partials + butterfly over le lanes
    float part[2][4];
    #pragma unroll
    for (int m = 0; m < 2; ++m)
        #pragma unroll
        for (int r = 0; r < 4; ++r) part[m][r] = 0.f;
    #pragma unroll
    for (int t = 0; t < 4; ++t) {
        const float bc = bc1[t * 16 + le];
        const float w2c = Wc2f[t * 16 + le];
        #pragma unroll
        for (int m = 0; m < 2; ++m)
            #pragma unroll
            for (int r = 0; r < 4; ++r)
                part[m][r] += silu_f(acc3[m][t][r] + bc) * w2c;
    }
    #pragma unroll
    for (int mask = 1; mask <= 8; mask <<= 1)
        #pragma unroll
        for (int m = 0; m < 2; ++m)
            #pragma unroll
            for (int r = 0; r < 4; ++r)
                part[m][r] += __shfl_xor(part[m][r], mask);

    // owner lanes le<8: one edge each; shfl pre-branch (all lanes active)
    const int rr = le & 3;
    const int sA = __shfl(s0, g * 4 + rr), sB = __shfl(s1, g * 4 + rr);
    const int dA = __shfl(d0, g * 4 + rr), dB = __shfl(d1, g * 4 + rr);

    if (le < 8) {
        const int m = le >> 2, r = le & 3;
        float v;
        if (m == 0) v = (r == 0) ? part[0][0] : (r == 1) ? part[0][1] : (r == 2) ? part[0][2] : part[0][3];
        else        v = (r == 0) ? part[1][0] : (r == 1) ? part[1][1] : (r == 2) ? part[1][2] : part[1][3];
        const int s = m ? sB : sA, d = m ? dB : dA;
        const float dx = coords[3 * s + 0] - coords[3 * d + 0];
        const float dy = coords[3 * s + 1] - coords[3 * d + 1];
        const float dz = coords[3 * s + 2] - coords[3 * d + 2];
        const float wq = v + bc2[0];
        const float inv = wq / (sqrtf(dx * dx + dy * dy + dz * dz) + 1e-8f);
        atomicAdd(&coord_acc[3 * d + 0], dx * inv);
        atomicAdd(&coord_acc[3 * d + 1], dy * inv);
        atomicAdd(&coord_acc[3 * d + 2], dz * inv);
    }
}

// ---------------- node update (MFMA, barrier-free, fp32 inputs) ----------------
__global__ __launch_bounds__(256, 2) void node_kernel(
    const float* __restrict__ nf, const float* __restrict__ coords,
    const short* __restrict__ wb,
    const float* __restrict__ bn1, const float* __restrict__ bn2,
    const float* __restrict__ aggr, const float* __restrict__ coord_acc,
    float* __restrict__ out)
{
    __shared__ short Hs[128][136];

    const int tid = threadIdx.x;
    const int wv = tid >> 6, lane = tid & 63, le = lane & 15, grp = lane >> 4;
    const int nb = blockIdx.x * 128, wbase = wv * 32;
    const int row0 = min(nb + wbase + le, NN - 1);
    const int row1 = min(nb + wbase + 16 + le, NN - 1);

    // MLP1: K=256 ([nf | aggr])
    f32x4 acc[2][8];
    #pragma unroll
    for (int m = 0; m < 2; ++m)
        #pragma unroll
        for (int t = 0; t < 8; ++t) acc[m][t] = (f32x4){0.f, 0.f, 0.f, 0.f};

    const short* w1 = wb + OFF_WN1T;
    #pragma unroll
    for (int kc = 0; kc < 8; ++kc) {
        const int gk = kc * 32 + grp * 8;
        const float* p0 = (kc < 4) ? nf + (size_t)row0 * 128 + gk : aggr + (size_t)row0 * 128 + gk - 128;
        const float* p1 = (kc < 4) ? nf + (size_t)row1 * 128 + gk : aggr + (size_t)row1 * 128 + gk - 128;
        const short8 a0 = cvt8(*(const float4*)p0, *(const float4*)(p0 + 4));
        const short8 a1 = cvt8(*(const float4*)p1, *(const float4*)(p1 + 4));
        short8 bfv[8];
        #pragma unroll
        for (int t = 0; t < 8; ++t)
            bfv[t] = *(const short8*)(w1 + (size_t)(t * 16 + le) * 256 + gk);
        #pragma unroll
        for (int t = 0; t < 8; ++t) {
            acc[0][t] = __builtin_amdgcn_mfma_f32_16x16x32_bf16(a0, bfv[t], acc[0][t], 0, 0, 0);
            acc[1][t] = __builtin_amdgcn_mfma_f32_16x16x32_bf16(a1, bfv[t], acc[1][t], 0, 0, 0);
        }
    }
    #pragma unroll
    for (int t = 0; t < 8; ++t) {
        const float b1 = bn1[t * 16 + le];
        #pragma unroll
        for (int m = 0; m < 2; ++m)
            #pragma unroll
            for (int r = 0; r < 4; ++r)
                Hs[wbase + m * 16 + grp * 4 + r][t * 16 + le] = f2bf(silu_f(acc[m][t][r] + b1));
    }

    // MLP2: K=128, then residual
    f32x4 acc2[2][8];
    #pragma unroll
    for (int m = 0; m < 2; ++m)
        #pragma unroll
        for (int t = 0; t < 8; ++t) acc2[m][t] = (f32x4){0.f, 0.f, 0.f, 0.f};

    const short* w2 = wb + OFF_WN2T;
    #pragma unroll
    for (int kc = 0; kc < 4; ++kc) {
        const int gk = kc * 32 + grp * 8;
        const short8 a0 = *(const short8*)&Hs[wbase + le][gk];
        const short8 a1 = *(const short8*)&Hs[wbase + 16 + le][gk];
        short8 bfv[8];
        #pragma unroll
        for (int t = 0; t < 8; ++t)
            bfv[t] = *(const short8*)(w2 + (size_t)(t * 16 + le) * 128 + gk);
        #pragma unroll
        for (int t = 0; t < 8; ++t) {
            acc2[0][t] = __builtin_amdgcn_mfma_f32_16x16x32_bf16(a0, bfv[t], acc2[0][t], 0, 0, 0);
            acc2[1][t] = __builtin_amdgcn_mfma_f32_16x16x32_bf16(a1, bfv[t], acc2[1][t], 0, 0, 0);
        }
    }
    #pragma unroll
    for (int t = 0; t < 8; ++t) {
        const float b2 = bn2[t * 16 + le];
        #pragma unroll
        for (int m = 0; m < 2; ++m)
            #pragma unroll
            for (int r = 0; r < 4; ++r) {
                const int row = nb + wbase + m * 16 + grp * 4 + r;
                if (row < NN) {
                    const int c = t * 16 + le;
                    out[(size_t)row * 128 + c] = acc2[m][t][r] + b2 + nf[(size_t)row * 128 + c];
                }
            }
    }

    // coords epilogue
    for (int i = tid; i < 384; i += 256) {
        const int n = nb + i / 3, j = i % 3;
        if (n < NN)
            out[(size_t)NN * 128 + 3 * n + j] = coords[3 * n + j] + coord_acc[3 * n + j];
    }
}

extern "C" void kernel_launch(void* const* d_in, const int* in_sizes, int n_in,
                              void* d_out, int out_size, void* d_ws, size_t ws_size,
                              hipStream_t stream)
{
    const float* node_feat  = (const float*)d_in[0];
    const float* edge_attr  = (const float*)d_in[1];
    const float* coords     = (const float*)d_in[2];
    const int*   edge_index = (const int*)d_in[3];
    const float* We1 = (const float*)d_in[4];
    const float* be1 = (const float*)d_in[5];
    const float* We2 = (const float*)d_in[6];
    const float* be2 = (const float*)d_in[7];
    const float* Wn1 = (const float*)d_in[8];
    const float* bn1 = (const float*)d_in[9];
    const float* Wn2 = (const float*)d_in[10];
    const float* bn2 = (const float*)d_in[11];
    const float* Wc1 = (const float*)d_in[12];
    const float* bc1 = (const float*)d_in[13];
    const float* Wc2 = (const float*)d_in[14];
    const float* bc2 = (const float*)d_in[15];
    float* out = (float*)d_out;

    const size_t sz_wb  = (size_t)W_TOTAL * 2;      // 229 KB
    const size_t sz_agg = (size_t)NN * 128 * 4;     // 25.6 MB
    const size_t sz_cac = (size_t)NN * 3 * 4;       // 600 KB
    const size_t sz_y   = (size_t)NN * 128 * 2;     // 12.8 MB each
    // total ~52 MB (< ~120 MB proven available in round 5)

    char* p = (char*)d_ws;
    short* wbf       = (short*)p;  p += sz_wb;
    float* aggr      = (float*)p;  p += sz_agg;
    float* coord_acc = (float*)p;  p += sz_cac;
    short* ysb       = (short*)p;  p += sz_y;
    short* ydb       = (short*)p;
    (void)ws_size;

    const int n4 = (NN * 128 + NN * 3) / 4;
    const int eg = NE / 128;                  // 3125
    const int ng = (NN + 127) / 128;          // 391

    prep_kernel<<<(W_TOTAL + 255) / 256, 256, 0, stream>>>(We1, We2, Wn1, Wn2, Wc1, wbf);
    zero_kernel<<<2048, 256, 0, stream>>>((float4*)aggr, n4);
    ynode_kernel<<<ng, 256, 0, stream>>>(node_feat, wbf, ysb, ydb);

    edge_kernel<<<eg, 256, 0, stream>>>(
        ysb, ydb, edge_attr, coords, edge_index, wbf,
        be1, be2, bc1, bc2, Wc2, aggr, coord_acc);

    node_kernel<<<ng, 256, 0, stream>>>(
        node_feat, coords, wbf, bn1, bn2, aggr, coord_acc, out);
}